// Round 13
// baseline (2940.436 us; speedup 1.0000x reference)
//
#include <hip/hip_runtime.h>
#include <hip/hip_bf16.h>

// VanillaRNN on MI355X — persistent cooperative kernel, v9: W_hh in AGPRs.
// h_t = tanh(x_t @ W_hx^T + h_{t-1} @ W_hh^T + b_hx + b_hh)  (hh term skipped at t=0)
// out = h_last @ W_out^T + b_out
//
// 12-round lesson: gfx950 512-thr blocks get 128 arch VGPRs + 128 AGPRs (unified
// file, 256/wave at 8 waves/CU). R6 (best) worked because the compiler placed
// whh[2][16]==128 regs into AGPRs; explicit W streaming (v8) thrashes L2 (8 MB
// W-slice/XCD/step through 4 MB) -> 4.26 GB HBM. v9 pins whh_a[4][8] (128 AGPR)
// explicitly and feeds MFMA A-operands from AGPR via inline asm "a" constraint.
// Per-step traffic: h only (L2-local sc0, counted vmcnt) + x (LLC) + 4 KB reduce.
// Row-partitioned XCDs: grp = XCC_ID owns 32 batch rows; slot = per-XCD atomic
// owns 64 hidden cols; wave kh owns K [kh*256,+256). Per-XCD 32-way barrier.

#define BB 256
#define SS 128
#define II 512
#define HH 2048
#define OO 10

#define NTHR 512
#define NBLK 256
#define LDS_BYTES 32768   // 4 regions * 8 KB reduce scratch (reused stage A/B)

typedef __attribute__((ext_vector_type(8))) __bf16 bf16x8;
typedef __attribute__((ext_vector_type(4))) __bf16 bf16x4;
typedef __attribute__((ext_vector_type(4))) float f32x4;
typedef unsigned long long u64;

__device__ __forceinline__ f32x4 mfma_(bf16x8 a, bf16x8 b, f32x4 c) {
    return __builtin_amdgcn_mfma_f32_16x16x32_bf16(a, b, c, 0, 0, 0);
}

__device__ __forceinline__ bf16x8 cvt8(float4 f0, float4 f1) {
    bf16x8 r;
    r[0] = (__bf16)f0.x; r[1] = (__bf16)f0.y; r[2] = (__bf16)f0.z; r[3] = (__bf16)f0.w;
    r[4] = (__bf16)f1.x; r[5] = (__bf16)f1.y; r[6] = (__bf16)f1.z; r[7] = (__bf16)f1.w;
    return r;
}

__global__ __launch_bounds__(256) void cvt_f32_bf16(const float* __restrict__ in,
                                                    __bf16* __restrict__ out, int n4) {
    int stride = gridDim.x * blockDim.x;
    for (int i = blockIdx.x * blockDim.x + threadIdx.x; i < n4; i += stride) {
        float4 v = reinterpret_cast<const float4*>(in)[i];
        bf16x4 o;
        o[0] = (__bf16)v.x; o[1] = (__bf16)v.y; o[2] = (__bf16)v.z; o[3] = (__bf16)v.w;
        *reinterpret_cast<bf16x4*>(out + 4 * (size_t)i) = o;
    }
}

#define AGLD(p) __hip_atomic_load((p), __ATOMIC_RELAXED, __HIP_MEMORY_SCOPE_AGENT)

// sc0 load: L1-bypass, agent-coherent; hits dirty same-XCD L2 h lines; TA-coalesced.
#define LDH(dst, base, off)                                                     \
    asm volatile("global_load_dwordx4 %0, %1, off offset:" #off " sc0"          \
                 : "=&v"(dst) : "v"(base));

#define WAITN(n)                                                                \
    asm volatile("s_waitcnt vmcnt(" #n ")" ::: "memory");                       \
    __builtin_amdgcn_sched_barrier(0);

// MFMA with A-operand straight from AGPR (gfx950: A may be AGPR, ISA §10).
#define MFMA_AG(ACC, WA, HB)                                                    \
    asm volatile("v_mfma_f32_16x16x32_bf16 %0, %1, %2, %0"                      \
                 : "+v"(ACC) : "a"(WA), "v"(HB));

// One K-chunk (kc): 4 col-frags x 2 row-frags = 8 MFMAs, W from AGPR.
#define MFMAK(KC, HA, HB)                                                       \
    MFMA_AG(acc[0][0], whh_a[0][KC], HA) MFMA_AG(acc[0][1], whh_a[0][KC], HB)   \
    MFMA_AG(acc[1][0], whh_a[1][KC], HA) MFMA_AG(acc[1][1], whh_a[1][KC], HB)   \
    MFMA_AG(acc[2][0], whh_a[2][KC], HA) MFMA_AG(acc[2][1], whh_a[2][KC], HB)   \
    MFMA_AG(acc[3][0], whh_a[3][KC], HA) MFMA_AG(acc[3][1], whh_a[3][KC], HB)

// 8 MFMAs via builtin (x-projection; all-VGPR operands).
#define MFMA8(W0, W1, W2, W3, HA, HB)                                           \
    acc[0][0] = mfma_(W0, HA, acc[0][0]); acc[0][1] = mfma_(W0, HB, acc[0][1]); \
    acc[1][0] = mfma_(W1, HA, acc[1][0]); acc[1][1] = mfma_(W1, HB, acc[1][1]); \
    acc[2][0] = mfma_(W2, HA, acc[2][0]); acc[2][1] = mfma_(W2, HB, acc[2][1]); \
    acc[3][0] = mfma_(W3, HA, acc[3][0]); acc[3][1] = mfma_(W3, HB, acc[3][1]);

extern "C" __global__ void __launch_bounds__(NTHR, 1) rnn_persist(
    const float*  __restrict__ x,      // [B][S][I] fp32
    const __bf16* __restrict__ Whh,    // [H][H] bf16 prepacked
    const __bf16* __restrict__ Whx,    // [H][I] bf16 prepacked
    const float*  __restrict__ bhx,    // [H]
    const float*  __restrict__ bhh,    // [H]
    __bf16* __restrict__ hb0,          // [B][H] ping
    __bf16* __restrict__ hb1,          // [B][H] pong
    unsigned* __restrict__ ctrs)       // [1024] zeroed: slot[g]=g*64, bar[g]=512+g*64
{
    extern __shared__ __align__(16) char lds[];
    const int tid = threadIdx.x;

    unsigned xcc;
    asm volatile("s_getreg_b32 %0, hwreg(HW_REG_XCC_ID)" : "=s"(xcc));
    const int grp = (int)(xcc & 7u);

    __shared__ unsigned slot_sh;
    if (tid == 0)
        slot_sh = __hip_atomic_fetch_add(ctrs + grp * 64, 1u, __ATOMIC_RELAXED,
                                         __HIP_MEMORY_SCOPE_AGENT);
    __syncthreads();
    const int slot = (int)(slot_sh & 31u);

    const int lane = tid & 63;
    const int kh   = tid >> 6;          // wave id 0..7 = K-slice [kh*256,+256)
    const int lq   = lane >> 4;         // 0..3
    const int lr   = lane & 15;
    const int colbase = slot * 64;      // hidden cols [colbase, +64)
    const int rowbase = grp * 32;       // batch rows  [rowbase, +32)

    const int ecol0 = colbase + (kh & 3) * 16 + 4 * lq;   // epilogue cols (kh<4)
    unsigned* bar = ctrs + 512 + grp * 64;
    char* red = lds;

    // ---- W_hh fragments -> AGPRs (persistent, 128 AGPR/lane; one-time load) ----
    // wave kh: cols colbase+cf*16+lr, K = kh*256 + kc*32 + lq*8.
    bf16x8 whh_a[4][8];
#pragma unroll
    for (int cf = 0; cf < 4; ++cf) {
        const __bf16* wp = Whh + (size_t)(colbase + cf * 16 + lr) * HH + kh * 256 + lq * 8;
#pragma unroll
        for (int kc = 0; kc < 8; ++kc) {
            whh_a[cf][kc] = *reinterpret_cast<const bf16x8*>(wp + kc * 32);
            asm volatile("" : "+a"(whh_a[cf][kc]));   // pin to AGPR class now
        }
    }

    for (int s = 0; s < SS - 1; ++s) {
        const __bf16* hrd = (s & 1) ? hb0 : hb1;
        __bf16*       hwr = (s & 1) ? hb1 : hb0;

        f32x4 acc[4][2] = {};   // [cf][rf]

        // ---- x-projection, K=512 split 8 ways (64/wave); overlaps barrier skew ----
#pragma unroll
        for (int kc = 0; kc < 2; ++kc) {
            bf16x8 wxf[4], xf[2];
#pragma unroll
            for (int cf = 0; cf < 4; ++cf)
                wxf[cf] = *reinterpret_cast<const bf16x8*>(
                    Whx + (size_t)(colbase + cf * 16 + lr) * II + kh * 64 + kc * 32 + lq * 8);
#pragma unroll
            for (int rf = 0; rf < 2; ++rf) {
                const float* xp = x + (size_t)(rowbase + rf * 16 + lr) * (SS * II)
                                  + (size_t)s * II + kh * 64 + kc * 32 + lq * 8;
                xf[rf] = cvt8(*reinterpret_cast<const float4*>(xp),
                              *reinterpret_cast<const float4*>(xp + 4));
            }
            MFMA8(wxf[0], wxf[1], wxf[2], wxf[3], xf[0], xf[1])
        }

        if (s > 0) {
            // ---- per-XCD barrier wait (arrivals of step s-1) ----
            if (tid == 0) {
                const unsigned target = (unsigned)s * 32u;
                unsigned polls = 0;
                while (AGLD(bar) < target) {
                    __builtin_amdgcn_s_sleep(1);
                    if (++polls > (1u << 20)) break;   // no-hang safety valve
                }
            }
            __syncthreads();

            // ---- hh: 16 h loads upfront (sc0), counted vmcnt, W from AGPR ----
            const char* p0 = (const char*)(hrd + (size_t)(rowbase + lr) * HH + kh * 256 + lq * 8);
            const char* p1 = (const char*)(hrd + (size_t)(rowbase + 16 + lr) * HH + kh * 256 + lq * 8);
            bf16x8 h0a, h0b, h1a, h1b, h2a, h2b, h3a, h3b;
            bf16x8 h4a, h4b, h5a, h5b, h6a, h6b, h7a, h7b;
            WAITN(0)   // drain x-phase loads: exact vmcnt baseline
            LDH(h0a, p0, 0)   LDH(h0b, p1, 0)
            LDH(h1a, p0, 64)  LDH(h1b, p1, 64)
            LDH(h2a, p0, 128) LDH(h2b, p1, 128)
            LDH(h3a, p0, 192) LDH(h3b, p1, 192)
            LDH(h4a, p0, 256) LDH(h4b, p1, 256)
            LDH(h5a, p0, 320) LDH(h5b, p1, 320)
            LDH(h6a, p0, 384) LDH(h6b, p1, 384)
            LDH(h7a, p0, 448) LDH(h7b, p1, 448)
            WAITN(12) MFMAK(0, h0a, h0b) MFMAK(1, h1a, h1b)
            WAITN(8)  MFMAK(2, h2a, h2b) MFMAK(3, h3a, h3b)
            WAITN(4)  MFMAK(4, h4a, h4b) MFMAK(5, h5a, h5b)
            WAITN(0)  MFMAK(6, h6a, h6b) MFMAK(7, h7a, h7b)
        }

        // ---- stage A: waves 4..7 -> red regions 0..3 ([j][lane] f32x4) ----
        if (kh >= 4) {
            char* base = red + (size_t)(kh - 4) * 8192 + (size_t)lane * 16;
#pragma unroll
            for (int cf = 0; cf < 4; ++cf)
#pragma unroll
                for (int rf = 0; rf < 2; ++rf)
                    *reinterpret_cast<f32x4*>(base + (cf * 2 + rf) * 1024) = acc[cf][rf];
        }
        __syncthreads();
        if (kh < 4) {
            char* base = red + (size_t)kh * 8192 + (size_t)lane * 16;
#pragma unroll
            for (int cf = 0; cf < 4; ++cf)
#pragma unroll
                for (int rf = 0; rf < 2; ++rf)
                    acc[cf][rf] += *reinterpret_cast<const f32x4*>(base + (cf * 2 + rf) * 1024);
            // ---- stage B (reuse same region): give away cf != kh slices ----
#pragma unroll
            for (int cf = 0; cf < 4; ++cf)
                if (cf != kh)
#pragma unroll
                    for (int rf = 0; rf < 2; ++rf)
                        *reinterpret_cast<f32x4*>(base + (cf * 2 + rf) * 1024) = acc[cf][rf];
        }
        __syncthreads();
        if (kh < 4) {
            // ---- collect partners' cf == kh slices, epilogue for 16 cols ----
#pragma unroll
            for (int p = 0; p < 4; ++p)
                if (p != kh) {
                    const char* pb = red + (size_t)p * 8192 + (size_t)lane * 16;
#pragma unroll
                    for (int rf = 0; rf < 2; ++rf)
                        acc[kh][rf] += *reinterpret_cast<const f32x4*>(pb + (kh * 2 + rf) * 1024);
                }
            const float4 bx4 = *reinterpret_cast<const float4*>(bhx + ecol0);
            const float4 bh4 = *reinterpret_cast<const float4*>(bhh + ecol0);
#pragma unroll
            for (int rf = 0; rf < 2; ++rf) {
                union { unsigned short u[4]; u64 ll; } P;
#pragma unroll
                for (int e = 0; e < 4; ++e) {
                    const float bias = ((const float*)&bx4)[e] +
                                       (s > 0 ? ((const float*)&bh4)[e] : 0.0f);
                    __bf16 v = (__bf16)tanhf(acc[kh][rf][e] + bias);
                    P.u[e] = __builtin_bit_cast(unsigned short, v);
                }
                *reinterpret_cast<u64*>(
                    hwr + (size_t)(rowbase + rf * 16 + lr) * HH + ecol0) = P.ll;
            }
            asm volatile("s_waitcnt vmcnt(0)" ::: "memory");   // stores in L2
        }
        __syncthreads();   // all stores of this step complete
        if (s < SS - 2 && tid == 0)
            __hip_atomic_fetch_add(bar, 1u, __ATOMIC_RELAXED, __HIP_MEMORY_SCOPE_AGENT);
    }
}

// out[b][o] = sum_h h[b][h] * W_out[o][h] + b_out[o]; one block per batch row.
__global__ __launch_bounds__(256) void rnn_out(
    const __bf16* __restrict__ h, const float* __restrict__ W_out,
    const float* __restrict__ b_out, float* __restrict__ out)
{
    const int b = blockIdx.x;
    const int tid = threadIdx.x;
    __shared__ float red[OO][4];

    float hv[8];
#pragma unroll
    for (int e = 0; e < 8; ++e)
        hv[e] = (float)h[(size_t)b * HH + tid + e * 256];

#pragma unroll
    for (int o = 0; o < OO; ++o) {
        float s = 0.0f;
#pragma unroll
        for (int e = 0; e < 8; ++e)
            s += hv[e] * W_out[(size_t)o * HH + tid + e * 256];
        for (int off = 32; off; off >>= 1) s += __shfl_down(s, off);
        if ((tid & 63) == 0) red[o][tid >> 6] = s;
    }
    __syncthreads();
    if (tid < OO) {
        float s = red[tid][0] + red[tid][1] + red[tid][2] + red[tid][3];
        out[(size_t)b * OO + tid] = s + b_out[tid];
    }
}

extern "C" void kernel_launch(void* const* d_in, const int* in_sizes, int n_in,
                              void* d_out, int out_size, void* d_ws, size_t ws_size,
                              hipStream_t stream) {
    (void)in_sizes; (void)n_in; (void)out_size; (void)ws_size;

    const float* x     = (const float*)d_in[0];
    const float* W_hx  = (const float*)d_in[1];
    const float* b_hx  = (const float*)d_in[2];
    const float* W_hh  = (const float*)d_in[3];
    const float* b_hh  = (const float*)d_in[4];
    const float* W_out = (const float*)d_in[5];
    const float* b_out = (const float*)d_in[6];
    float* out = (float*)d_out;

    char* ws = (char*)d_ws;
    __bf16*   hb0    = (__bf16*)ws;                                   // 1 MB
    __bf16*   hb1    = hb0 + (size_t)BB * HH;                         // 1 MB
    unsigned* ctrs   = (unsigned*)(ws + 2 * (size_t)BB * HH * 2);     // 4 KB
    __bf16*   Whh_bf = (__bf16*)(ws + 2 * (size_t)BB * HH * 2 + 4096);// 8 MB
    __bf16*   Whx_bf = Whh_bf + (size_t)HH * HH;                      // 2 MB

    hipMemsetAsync(ctrs, 0, 4096, stream);
    cvt_f32_bf16<<<1024, 256, 0, stream>>>(W_hh, Whh_bf, HH * HH / 4);
    cvt_f32_bf16<<<512, 256, 0, stream>>>(W_hx, Whx_bf, HH * II / 4);

    void* args[] = {(void*)&x, (void*)&Whh_bf, (void*)&Whx_bf, (void*)&b_hx,
                    (void*)&b_hh, (void*)&hb0, (void*)&hb1, (void*)&ctrs};
    hipError_t e = hipLaunchCooperativeKernel(
        reinterpret_cast<const void*>(rnn_persist),
        dim3(NBLK), dim3(NTHR), args, LDS_BYTES, stream);
    if (e != hipSuccess) {
        // Fallback: plain launch. 512 thr + 256 unified regs -> 1 block/CU,
        // grid == CU count, co-resident; barrier spin has a timeout anyway.
        rnn_persist<<<dim3(NBLK), dim3(NTHR), LDS_BYTES, stream>>>(
            x, Whh_bf, Whx_bf, b_hx, b_hh, hb0, hb1, ctrs);
    }

    // 127 steps: step s writes (s&1)?hb1:hb0; s=126 (even) -> hb0 holds h_last.
    rnn_out<<<BB, 256, 0, stream>>>(hb0, W_out, b_out, out);
}

// Round 14
// 1669.059 us; speedup vs baseline: 1.7617x; 1.7617x over previous
//
#include <hip/hip_runtime.h>
#include <hip/hip_bf16.h>

// VanillaRNN on MI355X — persistent cooperative kernel, v10.
// h_t = tanh(x_t @ W_hx^T + h_{t-1} @ W_hh^T + b_hx + b_hh)  (hh term skipped at t=0)
// out = h_last @ W_out^T + b_out
//
// = R6 (best, 1705 us; the only config with ZERO per-step W traffic: compiler
// placed whh[2][16]==128 regs in AGPRs, arch live set <=110) with ONE change:
// the hh h-loads go from per-lane 8B atomics (uncoalesced, full-drain waits)
// to coalesced global_load_dwordx4 sc0 asm with counted vmcnt(4) pipeline.
// Everything else is R6 verbatim: row-partitioned XCDs (grp=XCC_ID owns 32
// batch rows; slot=per-XCD atomic owns 64 hidden cols), 8 waves = 4 K-split x
// 2 col-groups, per-XCD 32-way barrier, plain h stores + vmcnt(0), 20-float
// stride LDS reduce (0 conflicts), launch_bounds(512,2).

#define BB 256
#define SS 128
#define II 512
#define HH 2048
#define OO 10

#define NTHR 512
#define NBLK 256
#define LDS_RED (6 * 64 * 20 * 4)   // 30720 B reduce scratch, 20-float lane stride

typedef __attribute__((ext_vector_type(8))) __bf16 bf16x8;
typedef __attribute__((ext_vector_type(4))) __bf16 bf16x4;
typedef __attribute__((ext_vector_type(4))) float f32x4;
typedef unsigned long long u64;

__device__ __forceinline__ f32x4 mfma_(bf16x8 a, bf16x8 b, f32x4 c) {
    return __builtin_amdgcn_mfma_f32_16x16x32_bf16(a, b, c, 0, 0, 0);
}

__device__ __forceinline__ bf16x8 cvt8(float4 f0, float4 f1) {
    bf16x8 r;
    r[0] = (__bf16)f0.x; r[1] = (__bf16)f0.y; r[2] = (__bf16)f0.z; r[3] = (__bf16)f0.w;
    r[4] = (__bf16)f1.x; r[5] = (__bf16)f1.y; r[6] = (__bf16)f1.z; r[7] = (__bf16)f1.w;
    return r;
}

__global__ __launch_bounds__(256) void cvt_f32_bf16(const float* __restrict__ in,
                                                    __bf16* __restrict__ out, int n4) {
    int stride = gridDim.x * blockDim.x;
    for (int i = blockIdx.x * blockDim.x + threadIdx.x; i < n4; i += stride) {
        float4 v = reinterpret_cast<const float4*>(in)[i];
        bf16x4 o;
        o[0] = (__bf16)v.x; o[1] = (__bf16)v.y; o[2] = (__bf16)v.z; o[3] = (__bf16)v.w;
        *reinterpret_cast<bf16x4*>(out + 4 * (size_t)i) = o;
    }
}

#define AGLD(p) __hip_atomic_load((p), __ATOMIC_RELAXED, __HIP_MEMORY_SCOPE_AGENT)

// sc0 load: L1-bypass, agent-coherent; hits dirty same-XCD L2 h lines; each
// instr = 16 fully-consumed 64B lines (lanes lq0..3 x 16B are contiguous/row).
#define LDH(dst, base, off)                                                     \
    asm volatile("global_load_dwordx4 %0, %1, off offset:" #off " sc0"          \
                 : "=&v"(dst) : "v"(base));

#define WAITN(n)                                                                \
    asm volatile("s_waitcnt vmcnt(" #n ")" ::: "memory");                       \
    __builtin_amdgcn_sched_barrier(0);

// Load group: 2 kc chunks (2 rows each) at byte offsets O1, O2 (4 loads).
#define LG(B, O1, O2)                                                           \
    LDH(B##0, p0, O1) LDH(B##1, p1, O1) LDH(B##2, p0, O2) LDH(B##3, p1, O2)

// Consume group: kc pair (K1 uses B0/B1, K2 uses B2/B3), 8 builtin MFMAs
// (A-operand whh[cf][kc] lives in AGPRs per the R6 allocation precedent).
#define MFMAG(B, K1, K2)                                                        \
    acc[0][0] = mfma_(whh[0][K1], B##0, acc[0][0]);                             \
    acc[0][1] = mfma_(whh[0][K1], B##1, acc[0][1]);                             \
    acc[1][0] = mfma_(whh[1][K1], B##0, acc[1][0]);                             \
    acc[1][1] = mfma_(whh[1][K1], B##1, acc[1][1]);                             \
    acc[0][0] = mfma_(whh[0][K2], B##2, acc[0][0]);                             \
    acc[0][1] = mfma_(whh[0][K2], B##3, acc[0][1]);                             \
    acc[1][0] = mfma_(whh[1][K2], B##2, acc[1][0]);                             \
    acc[1][1] = mfma_(whh[1][K2], B##3, acc[1][1]);

extern "C" __global__ void __launch_bounds__(NTHR, 2) rnn_persist(
    const float*  __restrict__ x,      // [B][S][I] fp32
    const __bf16* __restrict__ Whh,    // [H][H] bf16 prepacked
    const __bf16* __restrict__ Whx,    // [H][I] bf16 prepacked
    const float*  __restrict__ bhx,    // [H]
    const float*  __restrict__ bhh,    // [H]
    __bf16* __restrict__ hb0,          // [B][H] ping
    __bf16* __restrict__ hb1,          // [B][H] pong
    unsigned* __restrict__ ctrs)       // [1024] zeroed: slot[g]=g*64, bar[g]=512+g*64
{
    extern __shared__ __align__(16) float red[];
    const int tid = threadIdx.x;

    unsigned xcc;
    asm volatile("s_getreg_b32 %0, hwreg(HW_REG_XCC_ID)" : "=s"(xcc));
    const int grp = (int)(xcc & 7u);

    __shared__ unsigned slot_sh;
    if (tid == 0)
        slot_sh = __hip_atomic_fetch_add(ctrs + grp * 64, 1u, __ATOMIC_RELAXED,
                                         __HIP_MEMORY_SCOPE_AGENT);
    __syncthreads();
    const int slot = (int)(slot_sh & 31u);

    const int lane = tid & 63;
    const int wid  = tid >> 6;
    const int kh   = wid >> 1;          // 0..3  K-split (512 K each)
    const int cg   = wid & 1;           // 0..1  col-group
    const int lq   = lane >> 4;         // 0..3
    const int lr   = lane & 15;
    const int colbase = slot * 64 + cg * 32;   // hidden cols [colbase, +32)
    const int rowbase = grp * 32;              // batch rows  [rowbase, +32)

    // ---- W_hh fragments -> registers (128/lane; compiler -> AGPR, R6-proven) ----
    bf16x8 whh[2][16];
#pragma unroll
    for (int cf = 0; cf < 2; ++cf) {
        const __bf16* wp = Whh + (size_t)(colbase + cf * 16 + lr) * HH + kh * 512 + lq * 8;
#pragma unroll
        for (int kc = 0; kc < 16; ++kc)
            whh[cf][kc] = *reinterpret_cast<const bf16x8*>(wp + kc * 32);
    }

    unsigned* bar = ctrs + 512 + grp * 64;

    for (int s = 0; s < SS - 1; ++s) {
        const __bf16* hrd = (s & 1) ? hb0 : hb1;
        __bf16*       hwr = (s & 1) ? hb1 : hb0;

        f32x4 acc[2][2] = {};   // [cf][rf]

        // ---- x-projection (K=512 split 4 ways -> 128/wave); overlaps barrier skew ----
#pragma unroll
        for (int kc = 0; kc < 4; ++kc) {
            bf16x8 wxf[2], xf[2];
#pragma unroll
            for (int cf = 0; cf < 2; ++cf)
                wxf[cf] = *reinterpret_cast<const bf16x8*>(
                    Whx + (size_t)(colbase + cf * 16 + lr) * II + kh * 128 + kc * 32 + lq * 8);
#pragma unroll
            for (int rf = 0; rf < 2; ++rf) {
                const float* xp = x + (size_t)(rowbase + rf * 16 + lr) * (SS * II)
                                  + (size_t)s * II + kh * 128 + kc * 32 + lq * 8;
                xf[rf] = cvt8(*reinterpret_cast<const float4*>(xp),
                              *reinterpret_cast<const float4*>(xp + 4));
            }
#pragma unroll
            for (int cf = 0; cf < 2; ++cf)
#pragma unroll
                for (int rf = 0; rf < 2; ++rf)
                    acc[cf][rf] = mfma_(wxf[cf], xf[rf], acc[cf][rf]);
        }

        if (s > 0) {
            // ---- per-XCD barrier wait (arrivals of step s-1) ----
            if (tid == 0) {
                const unsigned target = (unsigned)s * 32u;
                unsigned polls = 0;
                while (AGLD(bar) < target) {
                    __builtin_amdgcn_s_sleep(1);
                    if (++polls > (1u << 20)) break;   // no-hang safety valve
                }
            }
            __syncthreads();

            // ---- hh: coalesced sc0 loads, 2-buffer pipeline, counted vmcnt(4) ----
            const char* p0 = (const char*)(hrd + (size_t)(rowbase + lr) * HH + kh * 512 + lq * 8);
            const char* p1 = (const char*)(hrd + (size_t)(rowbase + 16 + lr) * HH + kh * 512 + lq * 8);
            bf16x8 hA0, hA1, hA2, hA3, hB0, hB1, hB2, hB3;
            WAITN(0)   // drain x-phase loads: exact vmcnt baseline
            LG(hA, 0, 64)                              // kc0,1  ->  4 out
            LG(hB, 128, 192)                           // kc2,3  ->  8 out
            WAITN(4) MFMAG(hA, 0, 1)   LG(hA, 256, 320)   // kc4,5
            WAITN(4) MFMAG(hB, 2, 3)   LG(hB, 384, 448)   // kc6,7
            WAITN(4) MFMAG(hA, 4, 5)   LG(hA, 512, 576)   // kc8,9
            WAITN(4) MFMAG(hB, 6, 7)   LG(hB, 640, 704)   // kc10,11
            WAITN(4) MFMAG(hA, 8, 9)   LG(hA, 768, 832)   // kc12,13
            WAITN(4) MFMAG(hB, 10, 11) LG(hB, 896, 960)   // kc14,15
            WAITN(4) MFMAG(hA, 12, 13)
            WAITN(0) MFMAG(hB, 14, 15)
        }

        // ---- cross-wave K-reduction via LDS (20-float lane stride, 0 conflicts) ----
        if (kh > 0) {
            float* wp_ = red + ((size_t)(cg * 3 + kh - 1) * 64 + lane) * 20;
#pragma unroll
            for (int cf = 0; cf < 2; ++cf)
#pragma unroll
                for (int rf = 0; rf < 2; ++rf)
                    *reinterpret_cast<f32x4*>(wp_ + (cf * 2 + rf) * 4) = acc[cf][rf];
        }
        __syncthreads();   // SB1: partials visible
        if (kh == 0) {
#pragma unroll
            for (int w = 0; w < 3; ++w) {
                const float* rp = red + ((size_t)(cg * 3 + w) * 64 + lane) * 20;
#pragma unroll
                for (int cf = 0; cf < 2; ++cf)
#pragma unroll
                    for (int rf = 0; rf < 2; ++rf)
                        acc[cf][rf] += *reinterpret_cast<const f32x4*>(rp + (cf * 2 + rf) * 4);
            }
            // ---- epilogue: bias (L2) + tanh, one 8B store per (cf,rf) per lane ----
#pragma unroll
            for (int cf = 0; cf < 2; ++cf) {
                const int c0 = colbase + cf * 16 + 4 * lq;
                const float4 bx4 = *reinterpret_cast<const float4*>(bhx + c0);
                const float4 bh4 = *reinterpret_cast<const float4*>(bhh + c0);
#pragma unroll
                for (int rf = 0; rf < 2; ++rf) {
                    union { unsigned short u[4]; u64 ll; } P;
#pragma unroll
                    for (int e = 0; e < 4; ++e) {
                        const float bias = ((const float*)&bx4)[e] +
                                           (s > 0 ? ((const float*)&bh4)[e] : 0.0f);
                        __bf16 v = (__bf16)tanhf(acc[cf][rf][e] + bias);
                        P.u[e] = __builtin_bit_cast(unsigned short, v);
                    }
                    *reinterpret_cast<u64*>(
                        hwr + (size_t)(rowbase + rf * 16 + lr) * HH + c0) = P.ll;
                }
            }
            asm volatile("s_waitcnt vmcnt(0)" ::: "memory");   // stores in L2
        }
        __syncthreads();   // SB2: all stores of this step complete
        if (s < SS - 2 && tid == 0)
            __hip_atomic_fetch_add(bar, 1u, __ATOMIC_RELAXED, __HIP_MEMORY_SCOPE_AGENT);
    }
}

// out[b][o] = sum_h h[b][h] * W_out[o][h] + b_out[o]; one block per batch row.
__global__ __launch_bounds__(256) void rnn_out(
    const __bf16* __restrict__ h, const float* __restrict__ W_out,
    const float* __restrict__ b_out, float* __restrict__ out)
{
    const int b = blockIdx.x;
    const int tid = threadIdx.x;
    __shared__ float red[OO][4];

    float hv[8];
#pragma unroll
    for (int e = 0; e < 8; ++e)
        hv[e] = (float)h[(size_t)b * HH + tid + e * 256];

#pragma unroll
    for (int o = 0; o < OO; ++o) {
        float s = 0.0f;
#pragma unroll
        for (int e = 0; e < 8; ++e)
            s += hv[e] * W_out[(size_t)o * HH + tid + e * 256];
        for (int off = 32; off; off >>= 1) s += __shfl_down(s, off);
        if ((tid & 63) == 0) red[o][tid >> 6] = s;
    }
    __syncthreads();
    if (tid < OO) {
        float s = red[tid][0] + red[tid][1] + red[tid][2] + red[tid][3];
        out[(size_t)b * OO + tid] = s + b_out[tid];
    }
}

extern "C" void kernel_launch(void* const* d_in, const int* in_sizes, int n_in,
                              void* d_out, int out_size, void* d_ws, size_t ws_size,
                              hipStream_t stream) {
    (void)in_sizes; (void)n_in; (void)out_size; (void)ws_size;

    const float* x     = (const float*)d_in[0];
    const float* W_hx  = (const float*)d_in[1];
    const float* b_hx  = (const float*)d_in[2];
    const float* W_hh  = (const float*)d_in[3];
    const float* b_hh  = (const float*)d_in[4];
    const float* W_out = (const float*)d_in[5];
    const float* b_out = (const float*)d_in[6];
    float* out = (float*)d_out;

    char* ws = (char*)d_ws;
    __bf16*   hb0    = (__bf16*)ws;                                   // 1 MB
    __bf16*   hb1    = hb0 + (size_t)BB * HH;                         // 1 MB
    unsigned* ctrs   = (unsigned*)(ws + 2 * (size_t)BB * HH * 2);     // 4 KB
    __bf16*   Whh_bf = (__bf16*)(ws + 2 * (size_t)BB * HH * 2 + 4096);// 8 MB
    __bf16*   Whx_bf = Whh_bf + (size_t)HH * HH;                      // 2 MB

    hipMemsetAsync(ctrs, 0, 4096, stream);
    cvt_f32_bf16<<<1024, 256, 0, stream>>>(W_hh, Whh_bf, HH * HH / 4);
    cvt_f32_bf16<<<512, 256, 0, stream>>>(W_hx, Whx_bf, HH * II / 4);

    void* args[] = {(void*)&x, (void*)&Whh_bf, (void*)&Whx_bf, (void*)&b_hx,
                    (void*)&b_hh, (void*)&hb0, (void*)&hb1, (void*)&ctrs};
    hipError_t e = hipLaunchCooperativeKernel(
        reinterpret_cast<const void*>(rnn_persist),
        dim3(NBLK), dim3(NTHR), args, LDS_RED, stream);
    if (e != hipSuccess) {
        // Fallback: plain launch. 256 unified regs/wave -> 1 block/CU, grid ==
        // CU count, co-resident; barrier spin has a timeout regardless.
        rnn_persist<<<dim3(NBLK), dim3(NTHR), LDS_RED, stream>>>(
            x, Whh_bf, Whx_bf, b_hx, b_hh, hb0, hb1, ctrs);
    }

    // 127 steps: step s writes (s&1)?hb1:hb0; s=126 (even) -> hb0 holds h_last.
    rnn_out<<<BB, 256, 0, stream>>>(hb0, W_out, b_out, out);
}

// Round 16
// 1662.247 us; speedup vs baseline: 1.7690x; 1.0041x over previous
//
#include <hip/hip_runtime.h>
#include <hip/hip_bf16.h>

// VanillaRNN on MI355X — persistent cooperative kernel, v12.
// h_t = tanh(x_t @ W_hx^T + h_{t-1} @ W_hh^T + b_hx + b_hh)  (hh term skipped at t=0)
// out = h_last @ W_out^T + b_out
//
// = R14 (1669 us) + no-RMW barrier + quadrant-spread epilogue, with R15's bug
// fixed: ALL flag accesses are agent-scope atomics (LLC coherence point).
// R15 used a plain store for arrival -> stale dirty L2 flag lines from the
// previous graph replay survived the LLC memset -> barrier no-op'd -> tripwire.
// Atomic store (no RMW): 32 parallel arrivals to 32 distinct words, no
// serialized fetch_add chain on one line (R14's suspected ~4-9 us/step).
// Wait: wave 0 lanes each atomic-load one flag + __all ballot.
// Everything else R14-verbatim: row-partitioned XCDs (grp=XCC_ID owns 32
// batch rows; slot=per-XCD atomic owns 64 hidden cols), 8 waves = 4 K-split
// x 2 col-groups, whh[2][16] (128 regs -> compiler AGPR placement, zero
// per-step W traffic), coalesced sc0 h loads with counted vmcnt(4), plain h
// stores + vmcnt(0), 80B-stride conflict-free LDS reduce, launch_bounds(512,2).

#define BB 256
#define SS 128
#define II 512
#define HH 2048
#define OO 10

#define NTHR 512
#define NBLK 256
#define LDS_RED 40960   // 8 regions (cg,kh) x 64 lanes x 80 B (20-float stride)

typedef __attribute__((ext_vector_type(8))) __bf16 bf16x8;
typedef __attribute__((ext_vector_type(4))) __bf16 bf16x4;
typedef __attribute__((ext_vector_type(4))) float f32x4;
typedef unsigned long long u64;

__device__ __forceinline__ f32x4 mfma_(bf16x8 a, bf16x8 b, f32x4 c) {
    return __builtin_amdgcn_mfma_f32_16x16x32_bf16(a, b, c, 0, 0, 0);
}

__device__ __forceinline__ bf16x8 cvt8(float4 f0, float4 f1) {
    bf16x8 r;
    r[0] = (__bf16)f0.x; r[1] = (__bf16)f0.y; r[2] = (__bf16)f0.z; r[3] = (__bf16)f0.w;
    r[4] = (__bf16)f1.x; r[5] = (__bf16)f1.y; r[6] = (__bf16)f1.z; r[7] = (__bf16)f1.w;
    return r;
}

__global__ __launch_bounds__(256) void cvt_f32_bf16(const float* __restrict__ in,
                                                    __bf16* __restrict__ out, int n4) {
    int stride = gridDim.x * blockDim.x;
    for (int i = blockIdx.x * blockDim.x + threadIdx.x; i < n4; i += stride) {
        float4 v = reinterpret_cast<const float4*>(in)[i];
        bf16x4 o;
        o[0] = (__bf16)v.x; o[1] = (__bf16)v.y; o[2] = (__bf16)v.z; o[3] = (__bf16)v.w;
        *reinterpret_cast<bf16x4*>(out + 4 * (size_t)i) = o;
    }
}

#define AGLD(p) __hip_atomic_load((p), __ATOMIC_RELAXED, __HIP_MEMORY_SCOPE_AGENT)
#define AGST(p, v) __hip_atomic_store((p), (v), __ATOMIC_RELAXED, __HIP_MEMORY_SCOPE_AGENT)

// sc0 load: L1-bypass, agent-coherent; hits dirty same-XCD L2 h lines; each
// instr = 16 fully-consumed 64B lines.
#define LDH(dst, base, off)                                                     \
    asm volatile("global_load_dwordx4 %0, %1, off offset:" #off " sc0"          \
                 : "=&v"(dst) : "v"(base));

#define WAITN(n)                                                                \
    asm volatile("s_waitcnt vmcnt(" #n ")" ::: "memory");                       \
    __builtin_amdgcn_sched_barrier(0);

// Load group: 2 kc chunks (2 rows each) at byte offsets O1, O2 (4 loads).
#define LG(B, O1, O2)                                                           \
    LDH(B##0, p0, O1) LDH(B##1, p1, O1) LDH(B##2, p0, O2) LDH(B##3, p1, O2)

// Consume group: kc pair (K1 uses B0/B1, K2 uses B2/B3), 8 builtin MFMAs
// (A-operand whh[cf][kc] lives in AGPRs per the R6/R14 allocation precedent).
#define MFMAG(B, K1, K2)                                                        \
    acc[0][0] = mfma_(whh[0][K1], B##0, acc[0][0]);                             \
    acc[0][1] = mfma_(whh[0][K1], B##1, acc[0][1]);                             \
    acc[1][0] = mfma_(whh[1][K1], B##0, acc[1][0]);                             \
    acc[1][1] = mfma_(whh[1][K1], B##1, acc[1][1]);                             \
    acc[0][0] = mfma_(whh[0][K2], B##2, acc[0][0]);                             \
    acc[0][1] = mfma_(whh[0][K2], B##3, acc[0][1]);                             \
    acc[1][0] = mfma_(whh[1][K2], B##2, acc[1][0]);                             \
    acc[1][1] = mfma_(whh[1][K2], B##3, acc[1][1]);

extern "C" __global__ void __launch_bounds__(NTHR, 2) rnn_persist(
    const float*  __restrict__ x,      // [B][S][I] fp32
    const __bf16* __restrict__ Whh,    // [H][H] bf16 prepacked
    const __bf16* __restrict__ Whx,    // [H][I] bf16 prepacked
    const float*  __restrict__ bhx,    // [H]
    const float*  __restrict__ bhh,    // [H]
    __bf16* __restrict__ hb0,          // [B][H] ping
    __bf16* __restrict__ hb1,          // [B][H] pong
    unsigned* __restrict__ ctrs)       // [1024] zeroed: slot[g]=g*64, flags[g]=512+g*64+0..31
{
    extern __shared__ __align__(16) char lds[];
    const int tid = threadIdx.x;

    unsigned xcc;
    asm volatile("s_getreg_b32 %0, hwreg(HW_REG_XCC_ID)" : "=s"(xcc));
    const int grp = (int)(xcc & 7u);

    __shared__ unsigned slot_sh;
    if (tid == 0)
        slot_sh = __hip_atomic_fetch_add(ctrs + grp * 64, 1u, __ATOMIC_RELAXED,
                                         __HIP_MEMORY_SCOPE_AGENT);
    __syncthreads();
    const int slot = (int)(slot_sh & 31u);

    const int lane = tid & 63;
    const int wid  = tid >> 6;
    const int kh   = wid >> 1;          // 0..3  K-split (512 K each) + owned quadrant
    const int cg   = wid & 1;           // 0..1  col-group
    const int lq   = lane >> 4;         // 0..3
    const int lr   = lane & 15;
    const int colbase = slot * 64 + cg * 32;   // hidden cols [colbase, +32)
    const int rowbase = grp * 32;              // batch rows  [rowbase, +32)

    // ---- W_hh fragments -> registers (128/lane; compiler -> AGPR, proven) ----
    bf16x8 whh[2][16];
#pragma unroll
    for (int cf = 0; cf < 2; ++cf) {
        const __bf16* wp = Whh + (size_t)(colbase + cf * 16 + lr) * HH + kh * 512 + lq * 8;
#pragma unroll
        for (int kc = 0; kc < 16; ++kc)
            whh[cf][kc] = *reinterpret_cast<const bf16x8*>(wp + kc * 32);
    }

    unsigned* flags = ctrs + 512 + grp * 64;   // 32 x 4B per XCD

    for (int s = 0; s < SS - 1; ++s) {
        const __bf16* hrd = (s & 1) ? hb0 : hb1;
        __bf16*       hwr = (s & 1) ? hb1 : hb0;

        f32x4 acc[2][2] = {};   // [cf][rf]

        // ---- x-projection (K=512 split 4 ways -> 128/wave); overlaps barrier skew ----
#pragma unroll
        for (int kc = 0; kc < 4; ++kc) {
            bf16x8 wxf[2], xf[2];
#pragma unroll
            for (int cf = 0; cf < 2; ++cf)
                wxf[cf] = *reinterpret_cast<const bf16x8*>(
                    Whx + (size_t)(colbase + cf * 16 + lr) * II + kh * 128 + kc * 32 + lq * 8);
#pragma unroll
            for (int rf = 0; rf < 2; ++rf) {
                const float* xp = x + (size_t)(rowbase + rf * 16 + lr) * (SS * II)
                                  + (size_t)s * II + kh * 128 + kc * 32 + lq * 8;
                xf[rf] = cvt8(*reinterpret_cast<const float4*>(xp),
                              *reinterpret_cast<const float4*>(xp + 4));
            }
#pragma unroll
            for (int cf = 0; cf < 2; ++cf)
#pragma unroll
                for (int rf = 0; rf < 2; ++rf)
                    acc[cf][rf] = mfma_(wxf[cf], xf[rf], acc[cf][rf]);
        }

        if (s > 0) {
            // ---- barrier wait: wave 0 lanes atomic-load 32 flags (LLC) + ballot ----
            if (tid < 64) {
                const unsigned tgt = (unsigned)s;
                unsigned polls = 0;
                while (!__all((int)(AGLD(flags + (lane & 31)) >= tgt))) {
                    __builtin_amdgcn_s_sleep(1);
                    if (++polls > (1u << 20)) break;   // no-hang safety valve
                }
            }
            __syncthreads();

            // ---- hh: coalesced sc0 loads, 2-buffer pipeline, counted vmcnt(4) ----
            const char* p0 = (const char*)(hrd + (size_t)(rowbase + lr) * HH + kh * 512 + lq * 8);
            const char* p1 = (const char*)(hrd + (size_t)(rowbase + 16 + lr) * HH + kh * 512 + lq * 8);
            bf16x8 hA0, hA1, hA2, hA3, hB0, hB1, hB2, hB3;
            WAITN(0)   // drain x-phase loads: exact vmcnt baseline
            LG(hA, 0, 64)                              // kc0,1  ->  4 out
            LG(hB, 128, 192)                           // kc2,3  ->  8 out
            WAITN(4) MFMAG(hA, 0, 1)   LG(hA, 256, 320)   // kc4,5
            WAITN(4) MFMAG(hB, 2, 3)   LG(hB, 384, 448)   // kc6,7
            WAITN(4) MFMAG(hA, 4, 5)   LG(hA, 512, 576)   // kc8,9
            WAITN(4) MFMAG(hB, 6, 7)   LG(hB, 640, 704)   // kc10,11
            WAITN(4) MFMAG(hA, 8, 9)   LG(hA, 768, 832)   // kc12,13
            WAITN(4) MFMAG(hB, 10, 11) LG(hB, 896, 960)   // kc14,15
            WAITN(4) MFMAG(hA, 12, 13)
            WAITN(0) MFMAG(hB, 14, 15)
        }

        // ---- quadrant reduce: each wave gives away 3 quadrants (80B stride, 0-cfl) ----
        {
            char* reg0 = lds + ((size_t)(cg * 4 + kh) * 64 + lane) * 80;
#pragma unroll
            for (int q = 0; q < 4; ++q)
                if (q != kh)
                    *reinterpret_cast<f32x4*>(reg0 + q * 16) = acc[q >> 1][q & 1];
        }
        __syncthreads();
        // ---- own-quadrant finalize on ALL 8 waves: +3 partners, bias, 4 tanh, 1 store ----
        {
            f32x4 r = acc[kh >> 1][kh & 1];
#pragma unroll
            for (int p = 0; p < 4; ++p)
                if (p != kh) {
                    const char* pb = lds + ((size_t)(cg * 4 + p) * 64 + lane) * 80;
                    r += *reinterpret_cast<const f32x4*>(pb + kh * 16);
                }
            const int c0  = colbase + (kh >> 1) * 16 + 4 * lq;
            const int row = rowbase + (kh & 1) * 16 + lr;
            const float4 bx4 = *reinterpret_cast<const float4*>(bhx + c0);
            const float4 bh4 = *reinterpret_cast<const float4*>(bhh + c0);
            union { unsigned short u[4]; u64 ll; } P;
#pragma unroll
            for (int e = 0; e < 4; ++e) {
                const float bias = ((const float*)&bx4)[e] +
                                   (s > 0 ? ((const float*)&bh4)[e] : 0.0f);
                __bf16 v = (__bf16)tanhf(r[e] + bias);
                P.u[e] = __builtin_bit_cast(unsigned short, v);
            }
            *reinterpret_cast<u64*>(hwr + (size_t)row * HH + c0) = P.ll;
            asm volatile("s_waitcnt vmcnt(0)" ::: "memory");   // h store in L2
        }
        __syncthreads();   // all waves' stores of this step drained
        // ---- arrival: agent-scope atomic store (no RMW, LLC-coherent) ----
        if (s < SS - 2 && tid == 0)
            AGST(flags + slot, (unsigned)(s + 1));
    }
}

// out[b][o] = sum_h h[b][h] * W_out[o][h] + b_out[o]; one block per batch row.
__global__ __launch_bounds__(256) void rnn_out(
    const __bf16* __restrict__ h, const float* __restrict__ W_out,
    const float* __restrict__ b_out, float* __restrict__ out)
{
    const int b = blockIdx.x;
    const int tid = threadIdx.x;
    __shared__ float red[OO][4];

    float hv[8];
#pragma unroll
    for (int e = 0; e < 8; ++e)
        hv[e] = (float)h[(size_t)b * HH + tid + e * 256];

#pragma unroll
    for (int o = 0; o < OO; ++o) {
        float s = 0.0f;
#pragma unroll
        for (int e = 0; e < 8; ++e)
            s += hv[e] * W_out[(size_t)o * HH + tid + e * 256];
        for (int off = 32; off; off >>= 1) s += __shfl_down(s, off);
        if ((tid & 63) == 0) red[o][tid >> 6] = s;
    }
    __syncthreads();
    if (tid < OO) {
        float s = red[tid][0] + red[tid][1] + red[tid][2] + red[tid][3];
        out[(size_t)b * OO + tid] = s + b_out[tid];
    }
}

extern "C" void kernel_launch(void* const* d_in, const int* in_sizes, int n_in,
                              void* d_out, int out_size, void* d_ws, size_t ws_size,
                              hipStream_t stream) {
    (void)in_sizes; (void)n_in; (void)out_size; (void)ws_size;

    const float* x     = (const float*)d_in[0];
    const float* W_hx  = (const float*)d_in[1];
    const float* b_hx  = (const float*)d_in[2];
    const float* W_hh  = (const float*)d_in[3];
    const float* b_hh  = (const float*)d_in[4];
    const float* W_out = (const float*)d_in[5];
    const float* b_out = (const float*)d_in[6];
    float* out = (float*)d_out;

    char* ws = (char*)d_ws;
    __bf16*   hb0    = (__bf16*)ws;                                   // 1 MB
    __bf16*   hb1    = hb0 + (size_t)BB * HH;                         // 1 MB
    unsigned* ctrs   = (unsigned*)(ws + 2 * (size_t)BB * HH * 2);     // 4 KB
    __bf16*   Whh_bf = (__bf16*)(ws + 2 * (size_t)BB * HH * 2 + 4096);// 8 MB
    __bf16*   Whx_bf = Whh_bf + (size_t)HH * HH;                      // 2 MB

    hipMemsetAsync(ctrs, 0, 4096, stream);
    cvt_f32_bf16<<<1024, 256, 0, stream>>>(W_hh, Whh_bf, HH * HH / 4);
    cvt_f32_bf16<<<512, 256, 0, stream>>>(W_hx, Whx_bf, HH * II / 4);

    void* args[] = {(void*)&x, (void*)&Whh_bf, (void*)&Whx_bf, (void*)&b_hx,
                    (void*)&b_hh, (void*)&hb0, (void*)&hb1, (void*)&ctrs};
    hipError_t e = hipLaunchCooperativeKernel(
        reinterpret_cast<const void*>(rnn_persist),
        dim3(NBLK), dim3(NTHR), args, LDS_RED, stream);
    if (e != hipSuccess) {
        // Fallback: plain launch. 256 unified regs/wave -> 1 block/CU, grid ==
        // CU count, co-resident; barrier spin has a timeout regardless.
        rnn_persist<<<dim3(NBLK), dim3(NTHR), LDS_RED, stream>>>(
            x, Whh_bf, Whx_bf, b_hx, b_hh, hb0, hb1, ctrs);
    }

    // 127 steps: step s writes (s&1)?hb1:hb0; s=126 (even) -> hb0 holds h_last.
    rnn_out<<<BB, 256, 0, stream>>>(hb0, W_out, b_out, out);
}

// Round 17
// 1153.850 us; speedup vs baseline: 2.5484x; 1.4406x over previous
//
#include <hip/hip_runtime.h>
#include <hip/hip_bf16.h>

// VanillaRNN on MI355X — persistent cooperative kernel, v13: LDS-staged h.
// h_t = tanh(x_t @ W_hx^T + h_{t-1} @ W_hh^T + b_hx + b_hh)  (hh term skipped at t=0)
// out = h_last @ W_out^T + b_out
//
// R16 post-mortem: barrier mechanics were NOT the stall; the dominant cost is
// 8 MB/XCD/step of sc0 L2 reads (h slice read 64x: 32 blocks x 2 cg waves) at
// ~1-2 TB/s effective pure-L2 BW + per-fragment latency exposure.
// v13: after the barrier, the block burst-loads its 128 KB h slice ONCE into
// LDS (coalesced sc0 dwordx4, 2 rounds of 8/thread; (row&7)<<4 XOR layout) ->
// h L2 traffic halves to the 4 MB/XCD floor; hh B-fragments come from LDS.
// Reduce scratch overlays the dead h region (total LDS 131072 = proven max).
// x pre-converted to bf16. Unchanged: row-partitioned XCDs (grp=XCC_ID owns 32
// batch rows; slot=per-XCD atomic owns 64 hidden cols), 8 waves = 4 K-split x
// 2 col-groups, whh[2][16] -> compiler AGPR placement (zero per-step W traffic),
// R16 flag barrier (atomic store + ballot wait), quadrant-spread epilogue.

#define BB 256
#define SS 128
#define II 512
#define HH 2048
#define OO 10

#define NTHR 512
#define NBLK 256
#define LDS_BYTES 131072   // 128 KB h stage (32 rows x 4096 B, XOR-swizzled);
                           // reduce (40960 B) overlays it after hh completes.

typedef __attribute__((ext_vector_type(8))) __bf16 bf16x8;
typedef __attribute__((ext_vector_type(4))) __bf16 bf16x4;
typedef __attribute__((ext_vector_type(4))) float f32x4;
typedef unsigned long long u64;

__device__ __forceinline__ f32x4 mfma_(bf16x8 a, bf16x8 b, f32x4 c) {
    return __builtin_amdgcn_mfma_f32_16x16x32_bf16(a, b, c, 0, 0, 0);
}

__global__ __launch_bounds__(256) void cvt_f32_bf16(const float* __restrict__ in,
                                                    __bf16* __restrict__ out, int n4) {
    int stride = gridDim.x * blockDim.x;
    for (int i = blockIdx.x * blockDim.x + threadIdx.x; i < n4; i += stride) {
        float4 v = reinterpret_cast<const float4*>(in)[i];
        bf16x4 o;
        o[0] = (__bf16)v.x; o[1] = (__bf16)v.y; o[2] = (__bf16)v.z; o[3] = (__bf16)v.w;
        *reinterpret_cast<bf16x4*>(out + 4 * (size_t)i) = o;
    }
}

#define AGLD(p) __hip_atomic_load((p), __ATOMIC_RELAXED, __HIP_MEMORY_SCOPE_AGENT)
#define AGST(p, v) __hip_atomic_store((p), (v), __ATOMIC_RELAXED, __HIP_MEMORY_SCOPE_AGENT)

// sc0 load: L1-bypass, agent-coherent; hits dirty same-XCD L2 h lines.
#define LDP(dst, ptr)                                                           \
    asm volatile("global_load_dwordx4 %0, %1, off sc0" : "=&v"(dst) : "v"(ptr));

#define WAITN(n)                                                                \
    asm volatile("s_waitcnt vmcnt(" #n ")" ::: "memory");                       \
    __builtin_amdgcn_sched_barrier(0);

extern "C" __global__ void __launch_bounds__(NTHR, 2) rnn_persist(
    const __bf16* __restrict__ xbf,    // [B][S][I] bf16 prepacked
    const __bf16* __restrict__ Whh,    // [H][H] bf16 prepacked
    const __bf16* __restrict__ Whx,    // [H][I] bf16 prepacked
    const float*  __restrict__ bhx,    // [H]
    const float*  __restrict__ bhh,    // [H]
    __bf16* __restrict__ hb0,          // [B][H] ping
    __bf16* __restrict__ hb1,          // [B][H] pong
    unsigned* __restrict__ ctrs)       // [1024] zeroed: slot[g]=g*64, flags[g]=512+g*64+0..31
{
    extern __shared__ __align__(16) char lds[];
    const int tid = threadIdx.x;

    unsigned xcc;
    asm volatile("s_getreg_b32 %0, hwreg(HW_REG_XCC_ID)" : "=s"(xcc));
    const int grp = (int)(xcc & 7u);

    __shared__ unsigned slot_sh;
    if (tid == 0)
        slot_sh = __hip_atomic_fetch_add(ctrs + grp * 64, 1u, __ATOMIC_RELAXED,
                                         __HIP_MEMORY_SCOPE_AGENT);
    __syncthreads();
    const int slot = (int)(slot_sh & 31u);

    const int lane = tid & 63;
    const int wid  = tid >> 6;
    const int kh   = wid >> 1;          // 0..3  K-split (512 K each) + owned quadrant
    const int cg   = wid & 1;           // 0..1  col-group
    const int lq   = lane >> 4;         // 0..3
    const int lr   = lane & 15;
    const int colbase = slot * 64 + cg * 32;   // hidden cols [colbase, +32)
    const int rowbase = grp * 32;              // batch rows  [rowbase, +32)

    // ---- W_hh fragments -> registers (128/lane; compiler -> AGPR, proven) ----
    bf16x8 whh[2][16];
#pragma unroll
    for (int cf = 0; cf < 2; ++cf) {
        const __bf16* wp = Whh + (size_t)(colbase + cf * 16 + lr) * HH + kh * 512 + lq * 8;
#pragma unroll
        for (int kc = 0; kc < 16; ++kc)
            whh[cf][kc] = *reinterpret_cast<const bf16x8*>(wp + kc * 32);
    }

    unsigned* flags = ctrs + 512 + grp * 64;   // 32 x 4B per XCD

    // LDS h-read bases: row lr and lr+16, swizzle (row&7)<<4 (same for both).
    const unsigned swz = ((unsigned)(lr & 7)) << 4;
    const unsigned rb0 = (unsigned)lr * 4096u;
    const unsigned rb1 = (unsigned)(lr + 16) * 4096u;
    const unsigned ub  = ((unsigned)(kh * 64 + lq)) * 16u;   // + kc*64 per chunk
#define LDSH(RB, KC) (*reinterpret_cast<const bf16x8*>(                         \
        lds + ((RB + ub + (unsigned)(KC) * 64u) ^ swz)))

    for (int s = 0; s < SS - 1; ++s) {
        const __bf16* hrd = (s & 1) ? hb0 : hb1;
        __bf16*       hwr = (s & 1) ? hb1 : hb0;

        f32x4 acc[2][2] = {};   // [cf][rf]

        // ---- x-projection (bf16, K=512 split 4 ways); overlaps barrier skew ----
#pragma unroll
        for (int kc = 0; kc < 4; ++kc) {
            bf16x8 wxf[2], xf[2];
#pragma unroll
            for (int cf = 0; cf < 2; ++cf)
                wxf[cf] = *reinterpret_cast<const bf16x8*>(
                    Whx + (size_t)(colbase + cf * 16 + lr) * II + kh * 128 + kc * 32 + lq * 8);
#pragma unroll
            for (int rf = 0; rf < 2; ++rf)
                xf[rf] = *reinterpret_cast<const bf16x8*>(
                    xbf + (size_t)(rowbase + rf * 16 + lr) * (SS * II)
                    + (size_t)s * II + kh * 128 + kc * 32 + lq * 8);
#pragma unroll
            for (int cf = 0; cf < 2; ++cf)
#pragma unroll
                for (int rf = 0; rf < 2; ++rf)
                    acc[cf][rf] = mfma_(wxf[cf], xf[rf], acc[cf][rf]);
        }

        if (s > 0) {
            // ---- barrier wait: wave 0 lanes atomic-load 32 flags + ballot ----
            if (tid < 64) {
                const unsigned tgt = (unsigned)s;
                unsigned polls = 0;
                while (!__all((int)(AGLD(flags + (lane & 31)) >= tgt))) {
                    __builtin_amdgcn_s_sleep(1);
                    if (++polls > (1u << 20)) break;   // no-hang safety valve
                }
            }
            __syncthreads();

            // ---- stage h slice (128 KB) -> LDS: 16 coalesced sc0 dwordx4/thread ----
            {
                const char* pst = (const char*)(hrd + (size_t)rowbase * HH)
                                  + (size_t)tid * 16;
                uint4 sb[8];
                WAITN(0)   // exact vmcnt baseline (x-phase loads consumed)
#pragma unroll
                for (int j = 0; j < 8; ++j) LDP(sb[j], pst + j * 8192)
                WAITN(0)
#pragma unroll
                for (int j = 0; j < 8; ++j) {
                    const unsigned f = (unsigned)(tid + j * 512);
                    *reinterpret_cast<uint4*>(
                        lds + ((f * 16u) ^ (((f >> 8) & 7u) << 4))) = sb[j];
                }
#pragma unroll
                for (int j = 0; j < 8; ++j) LDP(sb[j], pst + (j + 8) * 8192)
                WAITN(0)
#pragma unroll
                for (int j = 0; j < 8; ++j) {
                    const unsigned f = (unsigned)(tid + (j + 8) * 512);
                    *reinterpret_cast<uint4*>(
                        lds + ((f * 16u) ^ (((f >> 8) & 7u) << 4))) = sb[j];
                }
            }
            __syncthreads();   // stage visible to all waves

            // ---- hh: A = whh (AGPR), B = h fragments from LDS ----
#pragma unroll
            for (int kc = 0; kc < 16; ++kc) {
                bf16x8 b0 = LDSH(rb0, kc);
                bf16x8 b1 = LDSH(rb1, kc);
                acc[0][0] = mfma_(whh[0][kc], b0, acc[0][0]);
                acc[0][1] = mfma_(whh[0][kc], b1, acc[0][1]);
                acc[1][0] = mfma_(whh[1][kc], b0, acc[1][0]);
                acc[1][1] = mfma_(whh[1][kc], b1, acc[1][1]);
            }
        }

        __syncthreads();   // all h-LDS reads done before reduce overlays region

        // ---- quadrant reduce (overlays LDS offset 0; 80B stride, conflict-free) ----
        {
            char* reg0 = lds + ((size_t)(cg * 4 + kh) * 64 + lane) * 80;
#pragma unroll
            for (int q = 0; q < 4; ++q)
                if (q != kh)
                    *reinterpret_cast<f32x4*>(reg0 + q * 16) = acc[q >> 1][q & 1];
        }
        __syncthreads();
        // ---- own-quadrant finalize on ALL 8 waves ----
        {
            f32x4 r = acc[kh >> 1][kh & 1];
#pragma unroll
            for (int p = 0; p < 4; ++p)
                if (p != kh) {
                    const char* pb = lds + ((size_t)(cg * 4 + p) * 64 + lane) * 80;
                    r += *reinterpret_cast<const f32x4*>(pb + kh * 16);
                }
            const int c0  = colbase + (kh >> 1) * 16 + 4 * lq;
            const int row = rowbase + (kh & 1) * 16 + lr;
            const float4 bx4 = *reinterpret_cast<const float4*>(bhx + c0);
            const float4 bh4 = *reinterpret_cast<const float4*>(bhh + c0);
            union { unsigned short u[4]; u64 ll; } P;
#pragma unroll
            for (int e = 0; e < 4; ++e) {
                const float bias = ((const float*)&bx4)[e] +
                                   (s > 0 ? ((const float*)&bh4)[e] : 0.0f);
                __bf16 v = (__bf16)tanhf(r[e] + bias);
                P.u[e] = __builtin_bit_cast(unsigned short, v);
            }
            *reinterpret_cast<u64*>(hwr + (size_t)row * HH + c0) = P.ll;
            asm volatile("s_waitcnt vmcnt(0)" ::: "memory");   // h store in L2
        }
        __syncthreads();   // all waves' stores of this step drained
        // ---- arrival: agent-scope atomic store (LLC-coherent, no RMW) ----
        if (s < SS - 2 && tid == 0)
            AGST(flags + slot, (unsigned)(s + 1));
    }
#undef LDSH
}

// out[b][o] = sum_h h[b][h] * W_out[o][h] + b_out[o]; one block per batch row.
__global__ __launch_bounds__(256) void rnn_out(
    const __bf16* __restrict__ h, const float* __restrict__ W_out,
    const float* __restrict__ b_out, float* __restrict__ out)
{
    const int b = blockIdx.x;
    const int tid = threadIdx.x;
    __shared__ float red[OO][4];

    float hv[8];
#pragma unroll
    for (int e = 0; e < 8; ++e)
        hv[e] = (float)h[(size_t)b * HH + tid + e * 256];

#pragma unroll
    for (int o = 0; o < OO; ++o) {
        float s = 0.0f;
#pragma unroll
        for (int e = 0; e < 8; ++e)
            s += hv[e] * W_out[(size_t)o * HH + tid + e * 256];
        for (int off = 32; off; off >>= 1) s += __shfl_down(s, off);
        if ((tid & 63) == 0) red[o][tid >> 6] = s;
    }
    __syncthreads();
    if (tid < OO) {
        float s = red[tid][0] + red[tid][1] + red[tid][2] + red[tid][3];
        out[(size_t)b * OO + tid] = s + b_out[tid];
    }
}

extern "C" void kernel_launch(void* const* d_in, const int* in_sizes, int n_in,
                              void* d_out, int out_size, void* d_ws, size_t ws_size,
                              hipStream_t stream) {
    (void)in_sizes; (void)n_in; (void)out_size; (void)ws_size;

    const float* x     = (const float*)d_in[0];
    const float* W_hx  = (const float*)d_in[1];
    const float* b_hx  = (const float*)d_in[2];
    const float* W_hh  = (const float*)d_in[3];
    const float* b_hh  = (const float*)d_in[4];
    const float* W_out = (const float*)d_in[5];
    const float* b_out = (const float*)d_in[6];
    float* out = (float*)d_out;

    char* ws = (char*)d_ws;
    __bf16*   hb0    = (__bf16*)ws;                                   // 1 MB
    __bf16*   hb1    = hb0 + (size_t)BB * HH;                         // 1 MB
    unsigned* ctrs   = (unsigned*)(ws + 2 * (size_t)BB * HH * 2);     // 4 KB
    __bf16*   Whh_bf = (__bf16*)(ws + 2 * (size_t)BB * HH * 2 + 4096);// 8 MB
    __bf16*   Whx_bf = Whh_bf + (size_t)HH * HH;                      // 2 MB
    __bf16*   xbf    = Whx_bf + (size_t)HH * II;                      // 33.6 MB

    hipMemsetAsync(ctrs, 0, 4096, stream);
    cvt_f32_bf16<<<1024, 256, 0, stream>>>(W_hh, Whh_bf, HH * HH / 4);
    cvt_f32_bf16<<<512, 256, 0, stream>>>(W_hx, Whx_bf, HH * II / 4);
    cvt_f32_bf16<<<4096, 256, 0, stream>>>(x, xbf, BB * SS * II / 4);

    static bool attr_set = false;   // host-side one-time setup (same effect every call)
    if (!attr_set) {
        hipFuncSetAttribute(reinterpret_cast<const void*>(rnn_persist),
                            hipFuncAttributeMaxDynamicSharedMemorySize, LDS_BYTES);
        attr_set = true;
    }

    void* args[] = {(void*)&xbf, (void*)&Whh_bf, (void*)&Whx_bf, (void*)&b_hx,
                    (void*)&b_hh, (void*)&hb0, (void*)&hb1, (void*)&ctrs};
    hipError_t e = hipLaunchCooperativeKernel(
        reinterpret_cast<const void*>(rnn_persist),
        dim3(NBLK), dim3(NTHR), args, LDS_BYTES, stream);
    if (e != hipSuccess) {
        // Fallback: plain launch. 128 KB LDS + 256 unified regs -> 1 block/CU,
        // grid == CU count, co-resident; barrier spin has a timeout regardless.
        rnn_persist<<<dim3(NBLK), dim3(NTHR), LDS_BYTES, stream>>>(
            xbf, Whh_bf, Whx_bf, b_hx, b_hh, hb0, hb1, ctrs);
    }

    // 127 steps: step s writes (s&1)?hb1:hb0; s=126 (even) -> hb0 holds h_last.
    rnn_out<<<BB, 256, 0, stream>>>(hb0, W_out, b_out, out);
}

// Round 19
// 849.768 us; speedup vs baseline: 3.4603x; 1.3578x over previous
//
#include <hip/hip_runtime.h>
#include <hip/hip_bf16.h>

// VanillaRNN on MI355X — persistent cooperative kernel, v15.
// h_t = tanh(x_t @ W_hx^T + h_{t-1} @ W_hh^T + b_hx + b_hh)  (hh term skipped at t=0)
// out = h_last @ W_out^T + b_out
//
// = R17/v13 (1154 us, PASS) with the h staging rebuilt to use ZERO VGPRs:
// R18 post-mortem: v14's sb[16] staging buffer spilled (128-VGPR arch cap with
// whh in 128 AGPRs) and spilled ASYNC asm-load destinations -> corruption.
// v13 itself spills a few regs/step (WRITE_SIZE 1.13 GB = 8.9 MB/step scratch
// writebacks ~ 3-4 us/step). v15: stage via __builtin_amdgcn_global_load_lds
// (direct global->LDS, 16 x 1KB per wave, ONE vmcnt exposure, no reg buffers).
// global_load_lds writes LDS linearly, so the XOR swizzle moves to the
// PRODUCER: epilogue stores h at pre-swizzled global addresses (bijective
// within each XCD-private 32-row slice); rnn_out un-XORs. LDS content and all
// fragment reads are bit-identical to v13. No sc0 needed: 128 KB/step of
// alternating-buffer streaming through 32 KB L1 guarantees eviction between
// reuses of a given h buffer (no stale-L1 window).
// Unchanged: row-partitioned XCDs (grp=XCC_ID owns 32 batch rows; slot=per-XCD
// atomic owns 64 hidden cols), 8 waves = 4 K-split x 2 col-groups, whh[2][16]
// -> compiler AGPR placement (zero per-step W traffic), agent-atomic flag
// barrier (R16/R17-proven), quadrant-spread epilogue, reduce overlays h-stage.

#define BB 256
#define SS 128
#define II 512
#define HH 2048
#define OO 10

#define NTHR 512
#define NBLK 256
#define LDS_BYTES 131072   // 128 KB h stage (32 rows x 4096 B, swizzled content);
                           // reduce (40960 B) overlays it after hh completes.

typedef __attribute__((ext_vector_type(8))) __bf16 bf16x8;
typedef __attribute__((ext_vector_type(4))) __bf16 bf16x4;
typedef __attribute__((ext_vector_type(4))) float f32x4;
typedef unsigned long long u64;

__device__ __forceinline__ f32x4 mfma_(bf16x8 a, bf16x8 b, f32x4 c) {
    return __builtin_amdgcn_mfma_f32_16x16x32_bf16(a, b, c, 0, 0, 0);
}

__global__ __launch_bounds__(256) void cvt_f32_bf16(const float* __restrict__ in,
                                                    __bf16* __restrict__ out, int n4) {
    int stride = gridDim.x * blockDim.x;
    for (int i = blockIdx.x * blockDim.x + threadIdx.x; i < n4; i += stride) {
        float4 v = reinterpret_cast<const float4*>(in)[i];
        bf16x4 o;
        o[0] = (__bf16)v.x; o[1] = (__bf16)v.y; o[2] = (__bf16)v.z; o[3] = (__bf16)v.w;
        *reinterpret_cast<bf16x4*>(out + 4 * (size_t)i) = o;
    }
}

#define AGLD(p) __hip_atomic_load((p), __ATOMIC_RELAXED, __HIP_MEMORY_SCOPE_AGENT)
#define AGST(p, v) __hip_atomic_store((p), (v), __ATOMIC_RELAXED, __HIP_MEMORY_SCOPE_AGENT)

#define WAITN(n)                                                                \
    asm volatile("s_waitcnt vmcnt(" #n ")" ::: "memory");                       \
    __builtin_amdgcn_sched_barrier(0);

typedef __attribute__((address_space(1))) const unsigned int* gptr_t;
typedef __attribute__((address_space(3))) unsigned int* lptr_t;

extern "C" __global__ void __launch_bounds__(NTHR, 2) rnn_persist(
    const __bf16* __restrict__ xbf,    // [B][S][I] bf16 prepacked
    const __bf16* __restrict__ Whh,    // [H][H] bf16 prepacked
    const __bf16* __restrict__ Whx,    // [H][I] bf16 prepacked
    const float*  __restrict__ bhx,    // [H]
    const float*  __restrict__ bhh,    // [H]
    __bf16* __restrict__ hb0,          // [B][H] ping (PRE-SWIZZLED layout)
    __bf16* __restrict__ hb1,          // [B][H] pong (PRE-SWIZZLED layout)
    unsigned* __restrict__ ctrs)       // [1024] zeroed: slot[g]=g*64, flags[g]=512+g*64+0..31
{
    extern __shared__ __align__(16) char lds[];
    const int tid = threadIdx.x;

    unsigned xcc;
    asm volatile("s_getreg_b32 %0, hwreg(HW_REG_XCC_ID)" : "=s"(xcc));
    const int grp = (int)(xcc & 7u);

    __shared__ unsigned slot_sh;
    if (tid == 0)
        slot_sh = __hip_atomic_fetch_add(ctrs + grp * 64, 1u, __ATOMIC_RELAXED,
                                         __HIP_MEMORY_SCOPE_AGENT);
    __syncthreads();
    const int slot = (int)(slot_sh & 31u);

    const int lane = tid & 63;
    const int wid  = tid >> 6;
    const int kh   = wid >> 1;          // 0..3  K-split (512 K each) + owned quadrant
    const int cg   = wid & 1;           // 0..1  col-group
    const int lq   = lane >> 4;         // 0..3
    const int lr   = lane & 15;
    const int colbase = slot * 64 + cg * 32;   // hidden cols [colbase, +32)
    const int rowbase = grp * 32;              // batch rows  [rowbase, +32)

    // ---- W_hh fragments -> registers (128/lane; compiler -> AGPR, proven) ----
    bf16x8 whh[2][16];
#pragma unroll
    for (int cf = 0; cf < 2; ++cf) {
        const __bf16* wp = Whh + (size_t)(colbase + cf * 16 + lr) * HH + kh * 512 + lq * 8;
#pragma unroll
        for (int kc = 0; kc < 16; ++kc)
            whh[cf][kc] = *reinterpret_cast<const bf16x8*>(wp + kc * 32);
    }

    unsigned* flags = ctrs + 512 + grp * 64;   // 32 x 4B per XCD

    // LDS h-read: rows lr and lr+16, swizzle (row&7)<<4 == (lr&7)<<4 for both.
    const unsigned swz = ((unsigned)(lr & 7)) << 4;
    const unsigned rb0 = (unsigned)lr * 4096u;
    const unsigned rb1 = (unsigned)(lr + 16) * 4096u;
    const unsigned ub  = ((unsigned)(kh * 64 + lq)) * 16u;
#define LDSH(RB, KC) (*reinterpret_cast<const bf16x8*>(                         \
        lds + ((RB + ub + (unsigned)(KC) * 64u) ^ swz)))

    for (int s = 0; s < SS - 1; ++s) {
        const __bf16* hrd = (s & 1) ? hb0 : hb1;
        __bf16*       hwr = (s & 1) ? hb1 : hb0;

        f32x4 acc[2][2] = {};   // [cf][rf]

        // ---- x-projection (bf16, K=512 split 4 ways); overlaps barrier skew ----
#pragma unroll
        for (int kc = 0; kc < 4; ++kc) {
            bf16x8 wxf[2], xf[2];
#pragma unroll
            for (int cf = 0; cf < 2; ++cf)
                wxf[cf] = *reinterpret_cast<const bf16x8*>(
                    Whx + (size_t)(colbase + cf * 16 + lr) * II + kh * 128 + kc * 32 + lq * 8);
#pragma unroll
            for (int rf = 0; rf < 2; ++rf)
                xf[rf] = *reinterpret_cast<const bf16x8*>(
                    xbf + (size_t)(rowbase + rf * 16 + lr) * (SS * II)
                    + (size_t)s * II + kh * 128 + kc * 32 + lq * 8);
#pragma unroll
            for (int cf = 0; cf < 2; ++cf)
#pragma unroll
                for (int rf = 0; rf < 2; ++rf)
                    acc[cf][rf] = mfma_(wxf[cf], xf[rf], acc[cf][rf]);
        }

        if (s > 0) {
            // ---- barrier wait: wave 0 lanes atomic-load 32 flags + ballot ----
            if (tid < 64) {
                const unsigned tgt = (unsigned)s;
                unsigned polls = 0;
                while (!__all((int)(AGLD(flags + (lane & 31)) >= tgt))) {
                    __builtin_amdgcn_s_sleep(1);
                    if (++polls > (1u << 20)) break;   // no-hang safety valve
                }
            }
            __syncthreads();

            // ---- stage h slice (128 KB) -> LDS via global_load_lds:
            //      zero reg buffers, one vmcnt exposure. LDS written linearly;
            //      data is pre-swizzled in global, so LDS content == v13. ----
            {
                const char* src = (const char*)hrd + (size_t)rowbase * 4096
                                  + (size_t)wid * 16384 + (size_t)lane * 16;
                char* dst = lds + (size_t)wid * 16384;
                WAITN(0)   // exact vmcnt baseline (x-phase loads drained)
#pragma unroll
                for (int j = 0; j < 16; ++j)
                    __builtin_amdgcn_global_load_lds(
                        (gptr_t)(src + j * 1024), (lptr_t)(dst + j * 1024), 16, 0, 0);
                WAITN(0)   // all 16 landed in LDS
            }
            __syncthreads();   // stage visible to all waves

            // ---- hh: A = whh (AGPR), B = h fragments from LDS ----
#pragma unroll
            for (int kc = 0; kc < 16; ++kc) {
                bf16x8 b0 = LDSH(rb0, kc);
                bf16x8 b1 = LDSH(rb1, kc);
                acc[0][0] = mfma_(whh[0][kc], b0, acc[0][0]);
                acc[0][1] = mfma_(whh[0][kc], b1, acc[0][1]);
                acc[1][0] = mfma_(whh[1][kc], b0, acc[1][0]);
                acc[1][1] = mfma_(whh[1][kc], b1, acc[1][1]);
            }
        }

        __syncthreads();   // all h-LDS reads done before reduce overlays region

        // ---- quadrant reduce (overlays LDS offset 0; 80B stride, conflict-free) ----
        {
            char* reg0 = lds + ((size_t)(cg * 4 + kh) * 64 + lane) * 80;
#pragma unroll
            for (int q = 0; q < 4; ++q)
                if (q != kh)
                    *reinterpret_cast<f32x4*>(reg0 + q * 16) = acc[q >> 1][q & 1];
        }
        __syncthreads();
        // ---- own-quadrant finalize on ALL 8 waves; PRE-SWIZZLED h store ----
        {
            f32x4 r = acc[kh >> 1][kh & 1];
#pragma unroll
            for (int p = 0; p < 4; ++p)
                if (p != kh) {
                    const char* pb = lds + ((size_t)(cg * 4 + p) * 64 + lane) * 80;
                    r += *reinterpret_cast<const f32x4*>(pb + kh * 16);
                }
            const int c0  = colbase + (kh >> 1) * 16 + 4 * lq;
            const int row = rowbase + (kh & 1) * 16 + lr;   // row&7 == lr&7
            const float4 bx4 = *reinterpret_cast<const float4*>(bhx + c0);
            const float4 bh4 = *reinterpret_cast<const float4*>(bhh + c0);
            union { unsigned short u[4]; u64 ll; } P;
#pragma unroll
            for (int e = 0; e < 4; ++e) {
                const float bias = ((const float*)&bx4)[e] +
                                   (s > 0 ? ((const float*)&bh4)[e] : 0.0f);
                __bf16 v = (__bf16)tanhf(r[e] + bias);
                P.u[e] = __builtin_bit_cast(unsigned short, v);
            }
            // store at swizzled in-row offset: (col*2) ^ ((row&7)<<4); 8B-aligned,
            // bijective (flips bits 4..6 of the in-row byte offset).
            *reinterpret_cast<u64*>(
                (char*)hwr + (size_t)row * 4096 +
                (((unsigned)(c0 * 2)) ^ (((unsigned)(lr & 7)) << 4))) = P.ll;
            asm volatile("s_waitcnt vmcnt(0)" ::: "memory");   // h store in L2
        }
        __syncthreads();   // all waves' stores of this step drained
        // ---- arrival: agent-scope atomic store (LLC-coherent, no RMW) ----
        if (s < SS - 2 && tid == 0)
            AGST(flags + slot, (unsigned)(s + 1));
    }
#undef LDSH
}

// out[b][o] = sum_h h[b][h] * W_out[o][h] + b_out[o]; one block per batch row.
// h is in the PRE-SWIZZLED layout: element [b][c] at byte b*4096 + ((c*2)^((b&7)<<4)).
__global__ __launch_bounds__(256) void rnn_out(
    const __bf16* __restrict__ h, const float* __restrict__ W_out,
    const float* __restrict__ b_out, float* __restrict__ out)
{
    const int b = blockIdx.x;
    const int tid = threadIdx.x;
    __shared__ float red[OO][4];

    const char* hb = (const char*)h + (size_t)b * 4096;
    const unsigned bswz = ((unsigned)(b & 7)) << 4;
    float hv[8];
#pragma unroll
    for (int e = 0; e < 8; ++e) {
        const unsigned off = ((unsigned)(tid + e * 256) * 2u) ^ bswz;
        hv[e] = (float)*reinterpret_cast<const __bf16*>(hb + off);
    }

#pragma unroll
    for (int o = 0; o < OO; ++o) {
        float s = 0.0f;
#pragma unroll
        for (int e = 0; e < 8; ++e)
            s += hv[e] * W_out[(size_t)o * HH + tid + e * 256];
        for (int off = 32; off; off >>= 1) s += __shfl_down(s, off);
        if ((tid & 63) == 0) red[o][tid >> 6] = s;
    }
    __syncthreads();
    if (tid < OO) {
        float s = red[tid][0] + red[tid][1] + red[tid][2] + red[tid][3];
        out[(size_t)b * OO + tid] = s + b_out[tid];
    }
}

extern "C" void kernel_launch(void* const* d_in, const int* in_sizes, int n_in,
                              void* d_out, int out_size, void* d_ws, size_t ws_size,
                              hipStream_t stream) {
    (void)in_sizes; (void)n_in; (void)out_size; (void)ws_size;

    const float* x     = (const float*)d_in[0];
    const float* W_hx  = (const float*)d_in[1];
    const float* b_hx  = (const float*)d_in[2];
    const float* W_hh  = (const float*)d_in[3];
    const float* b_hh  = (const float*)d_in[4];
    const float* W_out = (const float*)d_in[5];
    const float* b_out = (const float*)d_in[6];
    float* out = (float*)d_out;

    char* ws = (char*)d_ws;
    __bf16*   hb0    = (__bf16*)ws;                                   // 1 MB
    __bf16*   hb1    = hb0 + (size_t)BB * HH;                         // 1 MB
    unsigned* ctrs   = (unsigned*)(ws + 2 * (size_t)BB * HH * 2);     // 4 KB
    __bf16*   Whh_bf = (__bf16*)(ws + 2 * (size_t)BB * HH * 2 + 4096);// 8 MB
    __bf16*   Whx_bf = Whh_bf + (size_t)HH * HH;                      // 2 MB
    __bf16*   xbf    = Whx_bf + (size_t)HH * II;                      // 33.6 MB

    hipMemsetAsync(ctrs, 0, 4096, stream);
    cvt_f32_bf16<<<1024, 256, 0, stream>>>(W_hh, Whh_bf, HH * HH / 4);
    cvt_f32_bf16<<<512, 256, 0, stream>>>(W_hx, Whx_bf, HH * II / 4);
    cvt_f32_bf16<<<4096, 256, 0, stream>>>(x, xbf, BB * SS * II / 4);

    static bool attr_set = false;   // host-side one-time setup (same effect every call)
    if (!attr_set) {
        hipFuncSetAttribute(reinterpret_cast<const void*>(rnn_persist),
                            hipFuncAttributeMaxDynamicSharedMemorySize, LDS_BYTES);
        attr_set = true;
    }

    void* args[] = {(void*)&xbf, (void*)&Whh_bf, (void*)&Whx_bf, (void*)&b_hx,
                    (void*)&b_hh, (void*)&hb0, (void*)&hb1, (void*)&ctrs};
    hipError_t e = hipLaunchCooperativeKernel(
        reinterpret_cast<const void*>(rnn_persist),
        dim3(NBLK), dim3(NTHR), args, LDS_BYTES, stream);
    if (e != hipSuccess) {
        // Fallback: plain launch. 128 KB LDS + 256 unified regs -> 1 block/CU,
        // grid == CU count, co-resident; barrier spin has a timeout regardless.
        rnn_persist<<<dim3(NBLK), dim3(NTHR), LDS_BYTES, stream>>>(
            xbf, Whh_bf, Whx_bf, b_hx, b_hh, hb0, hb1, ctrs);
    }

    // 127 steps: step s writes (s&1)?hb1:hb0; s=126 (even) -> hb0 holds h_last.
    rnn_out<<<BB, 256, 0, stream>>>(hb0, W_out, b_out, out);
}